// Round 2
// baseline (630.805 us; speedup 1.0000x reference)
//
#include <hip/hip_runtime.h>
#include <hip/hip_bf16.h>

#define Bn 128
#define Hd 512
#define Nn 1024

typedef __attribute__((ext_vector_type(8))) short short8;
typedef __attribute__((ext_vector_type(4))) float f32x4;

__device__ __forceinline__ unsigned short f2bf(float f) {
    unsigned x;
    __builtin_memcpy(&x, &f, 4);
    unsigned r = x + 0x7fffu + ((x >> 16) & 1u);
    return (unsigned short)(r >> 16);
}

__device__ __forceinline__ float wave_sum(float v) {
    v += __shfl_xor(v, 32);
    v += __shfl_xor(v, 16);
    v += __shfl_xor(v, 8);
    v += __shfl_xor(v, 4);
    v += __shfl_xor(v, 2);
    v += __shfl_xor(v, 1);
    return v;
}

__device__ __forceinline__ float tanh_fast(float x) {
    float e = __expf(2.0f * x);
    return 1.0f - 2.0f / (e + 1.0f);
}

// ---------------------------------------------------------------------------
// K0: Wb[h][k] = bf16(attn_W[h][k]) for k in [0,512)  (the sn-half of W)
// ---------------------------------------------------------------------------
__global__ void convert_W_kernel(const float* __restrict__ attn_W,
                                 unsigned short* __restrict__ Wb) {
    int idx = (blockIdx.x * 256 + threadIdx.x) * 8;  // [0, 512*512)
    int h = idx >> 9;
    int k = idx & 511;
    const float* p = attn_W + (size_t)h * 1024 + k;
    float4 v0 = *(const float4*)p;
    float4 v1 = *(const float4*)(p + 4);
    unsigned short t[8] = {f2bf(v0.x), f2bf(v0.y), f2bf(v0.z), f2bf(v0.w),
                           f2bf(v1.x), f2bf(v1.y), f2bf(v1.z), f2bf(v1.w)};
    *(uint4*)(Wb + idx) = *(uint4*)t;
}

// ---------------------------------------------------------------------------
// K1: mc_term[b,h] = sum_k attn_W[h, 512+k] * mc_hidden[b,k]   (fp32 exact)
// wave per (b,h); K=512 = 64 lanes x 8
// ---------------------------------------------------------------------------
__global__ void mc_term_kernel(const float* __restrict__ mc,
                               const float* __restrict__ attn_W,
                               float* __restrict__ mc_term) {
    int wg = (blockIdx.x * blockDim.x + threadIdx.x) >> 6;
    int lane = threadIdx.x & 63;
    int b = wg >> 9;
    int h = wg & 511;
    const float* m = mc + b * Hd + lane * 8;
    const float* w = attn_W + (size_t)h * 1024 + 512 + lane * 8;
    float4 m0 = *(const float4*)m, m1 = *(const float4*)(m + 4);
    float4 w0 = *(const float4*)w, w1 = *(const float4*)(w + 4);
    float acc = m0.x * w0.x + m0.y * w0.y + m0.z * w0.z + m0.w * w0.w +
                m1.x * w1.x + m1.y * w1.y + m1.z * w1.z + m1.w * w1.w;
    acc = wave_sum(acc);
    if (lane == 0) mc_term[b * Hd + h] = acc;
}

// ---------------------------------------------------------------------------
// K2: scores[b,n] = sum_h attn_v[h] * tanh( sum_k W1[h,k]*sn[b,k,n] + mc_term[b,h] )
// WG = (b, 64-wide n tile). M=512 (4 waves x 128), K chunks of 64.
// A-frags from bf16 Wb (global, L2-hot); sn staged fp32->bf16 transposed in LDS.
// ---------------------------------------------------------------------------
__global__ __launch_bounds__(256, 2)
void attn_score_kernel(const float* __restrict__ sn,
                       const unsigned short* __restrict__ Wb,
                       const float* __restrict__ attn_v,
                       const float* __restrict__ mc_term,
                       float* __restrict__ scores) {
    __shared__ __align__(16) unsigned short snT[64][72];
    __shared__ float av_s[512];
    __shared__ float mct_s[512];
    __shared__ float ssum[64];

    const int b = blockIdx.x >> 4;
    const int n0 = (blockIdx.x & 15) * 64;
    const int tid = threadIdx.x;
    const int lane = tid & 63;
    const int wid = tid >> 6;
    const int quad = lane >> 4;
    const int l15 = lane & 15;
    const int m0 = wid * 128;

    av_s[tid] = attn_v[tid];
    av_s[tid + 256] = attn_v[tid + 256];
    mct_s[tid] = mc_term[b * Hd + tid];
    mct_s[tid + 256] = mc_term[b * Hd + tid + 256];

    f32x4 acc[8][4];
#pragma unroll
    for (int i = 0; i < 8; ++i)
#pragma unroll
        for (int j = 0; j < 4; ++j) {
            f32x4 z = {0.f, 0.f, 0.f, 0.f};
            acc[i][j] = z;
        }

    const short* W = (const short*)Wb;

    for (int k0 = 0; k0 < 512; k0 += 64) {
        // stage sn[b, k0..k0+63, n0..n0+63] -> snT[n][k] (bf16)
#pragma unroll
        for (int j = 0; j < 2; ++j) {
            int c = tid + j * 256;        // [0,512)
            int n = c & 63;
            int kb = (c >> 6) * 8;        // j=0: 0..24, j=1: 32..56
            const float* p = sn + ((size_t)(b * Hd + k0 + kb)) * Nn + n0 + n;
            unsigned short t[8];
#pragma unroll
            for (int i = 0; i < 8; ++i) t[i] = f2bf(p[(size_t)i * Nn]);
            *(uint4*)&snT[n][kb] = *(uint4*)t;
        }
        __syncthreads();
#pragma unroll
        for (int kk = 0; kk < 64; kk += 32) {
            short8 bfr[4];
#pragma unroll
            for (int nt = 0; nt < 4; ++nt)
                bfr[nt] = *(const short8*)&snT[nt * 16 + l15][kk + quad * 8];
#pragma unroll
            for (int mt = 0; mt < 8; ++mt) {
                const short8 aw =
                    *(const short8*)(W + (size_t)(m0 + mt * 16 + l15) * 512 + k0 + kk + quad * 8);
#pragma unroll
                for (int nt = 0; nt < 4; ++nt)
                    acc[mt][nt] = __builtin_amdgcn_mfma_f32_16x16x32_bf16(aw, bfr[nt], acc[mt][nt], 0, 0, 0);
            }
        }
        __syncthreads();
    }

    // epilogue: tanh + attn_v dot, reduce over h
    float s[4] = {0.f, 0.f, 0.f, 0.f};
#pragma unroll
    for (int mt = 0; mt < 8; ++mt) {
        int hb = m0 + mt * 16 + quad * 4;
#pragma unroll
        for (int r = 0; r < 4; ++r) {
            float av = av_s[hb + r];
            float mcv = mct_s[hb + r];
#pragma unroll
            for (int nt = 0; nt < 4; ++nt)
                s[nt] += av * tanh_fast(acc[mt][nt][r] + mcv);
        }
    }
    if (tid < 64) ssum[tid] = 0.f;
    __syncthreads();
#pragma unroll
    for (int nt = 0; nt < 4; ++nt) {
        float v = s[nt];
        v += __shfl_xor(v, 16);
        v += __shfl_xor(v, 32);
        if (lane < 16) atomicAdd(&ssum[nt * 16 + l15], v);
    }
    __syncthreads();
    if (tid < 64) scores[b * Nn + n0 + tid] = ssum[tid];
}

// ---------------------------------------------------------------------------
// K3: softmax over n per batch row (in-place on scores)
// ---------------------------------------------------------------------------
__global__ void softmax_kernel(float* __restrict__ scores) {
    const int b = blockIdx.x;
    const int tid = threadIdx.x;
    const int lane = tid & 63, wid = tid >> 6;
    __shared__ float red[4];
    float v[4];
#pragma unroll
    for (int i = 0; i < 4; ++i) v[i] = scores[b * Nn + tid + i * 256];
    float m = fmaxf(fmaxf(v[0], v[1]), fmaxf(v[2], v[3]));
#pragma unroll
    for (int off = 32; off >= 1; off >>= 1) m = fmaxf(m, __shfl_xor(m, off));
    if (lane == 0) red[wid] = m;
    __syncthreads();
    m = fmaxf(fmaxf(red[0], red[1]), fmaxf(red[2], red[3]));
    __syncthreads();
    float s = 0.f;
#pragma unroll
    for (int i = 0; i < 4; ++i) {
        v[i] = __expf(v[i] - m);
        s += v[i];
    }
    s = wave_sum(s);
    if (lane == 0) red[wid] = s;
    __syncthreads();
    s = red[0] + red[1] + red[2] + red[3];
    float inv = 1.0f / s;
#pragma unroll
    for (int i = 0; i < 4; ++i) scores[b * Nn + tid + i * 256] = v[i] * inv;
}

// ---------------------------------------------------------------------------
// K4: context[b,h] = sum_n attns[b,n] * sn[b,h,n]   (wave per (b,h) row, fp32)
// ---------------------------------------------------------------------------
__global__ void context_kernel(const float* __restrict__ sn,
                               const float* __restrict__ attns,
                               float* __restrict__ context) {
    int wg = (blockIdx.x * blockDim.x + threadIdx.x) >> 6;
    int lane = threadIdx.x & 63;
    int b = wg >> 9, h = wg & 511;
    const float* row = sn + ((size_t)(b * Hd + h)) * Nn;
    const float* at = attns + b * Nn;
    float acc = 0.f;
#pragma unroll
    for (int i = 0; i < 2; ++i) {
        int n = i * 512 + lane * 8;
        float4 s0 = *(const float4*)(row + n);
        float4 s1 = *(const float4*)(row + n + 4);
        float4 a0 = *(const float4*)(at + n);
        float4 a1 = *(const float4*)(at + n + 4);
        acc += s0.x * a0.x + s0.y * a0.y + s0.z * a0.z + s0.w * a0.w;
        acc += s1.x * a1.x + s1.y * a1.y + s1.z * a1.z + s1.w * a1.w;
    }
    acc = wave_sum(acc);
    if (lane == 0) context[b * Hd + h] = acc;
}

// ---------------------------------------------------------------------------
// K5: out1[b,h] = relu( dot([mc|context], fc1_W[h,:]) + fc1_b[h] )   (fp32)
// ---------------------------------------------------------------------------
__global__ void fc1_kernel(const float* __restrict__ mc,
                           const float* __restrict__ ctx,
                           const float* __restrict__ fc1_W,
                           const float* __restrict__ fc1_b,
                           float* __restrict__ out1) {
    int wg = (blockIdx.x * blockDim.x + threadIdx.x) >> 6;
    int lane = threadIdx.x & 63;
    int b = wg >> 9, h = wg & 511;
    const float* wr = fc1_W + (size_t)h * 1024;
    float acc = 0.f;
    {
        float4 w0 = *(const float4*)(wr + lane * 8);
        float4 w1 = *(const float4*)(wr + lane * 8 + 4);
        float4 x0 = *(const float4*)(mc + b * Hd + lane * 8);
        float4 x1 = *(const float4*)(mc + b * Hd + lane * 8 + 4);
        acc += w0.x * x0.x + w0.y * x0.y + w0.z * x0.z + w0.w * x0.w;
        acc += w1.x * x1.x + w1.y * x1.y + w1.z * x1.z + w1.w * x1.w;
    }
    {
        float4 w0 = *(const float4*)(wr + 512 + lane * 8);
        float4 w1 = *(const float4*)(wr + 512 + lane * 8 + 4);
        float4 x0 = *(const float4*)(ctx + b * Hd + lane * 8);
        float4 x1 = *(const float4*)(ctx + b * Hd + lane * 8 + 4);
        acc += w0.x * x0.x + w0.y * x0.y + w0.z * x0.z + w0.w * x0.w;
        acc += w1.x * x1.x + w1.y * x1.y + w1.z * x1.z + w1.w * x1.w;
    }
    acc = wave_sum(acc);
    if (lane == 0) out1[b * Hd + h] = fmaxf(acc + fc1_b[h], 0.f);
}

// ---------------------------------------------------------------------------
// K6: out2[b,h] = relu( dot(out1, fc2_W[h,:]) + fc2_b[h] )   (fp32)
// ---------------------------------------------------------------------------
__global__ void fc2_kernel(const float* __restrict__ out1,
                           const float* __restrict__ fc2_W,
                           const float* __restrict__ fc2_b,
                           float* __restrict__ out2) {
    int wg = (blockIdx.x * blockDim.x + threadIdx.x) >> 6;
    int lane = threadIdx.x & 63;
    int b = wg >> 9, h = wg & 511;
    const float* wr = fc2_W + (size_t)h * 512 + lane * 8;
    float4 w0 = *(const float4*)wr;
    float4 w1 = *(const float4*)(wr + 4);
    float4 x0 = *(const float4*)(out1 + b * Hd + lane * 8);
    float4 x1 = *(const float4*)(out1 + b * Hd + lane * 8 + 4);
    float acc = w0.x * x0.x + w0.y * x0.y + w0.z * x0.z + w0.w * x0.w +
                w1.x * x1.x + w1.y * x1.y + w1.z * x1.z + w1.w * x1.w;
    acc = wave_sum(acc);
    if (lane == 0) out2[b * Hd + h] = fmaxf(acc + fc2_b[h], 0.f);
}

// ---------------------------------------------------------------------------
// K7: probs[b,n] = sum_h ptr_v[h] * tanh( sn[b,h,n] + out2[b,h] )   (fp32)
// block = (b, 512-wide n half); thread handles 2 adjacent n (float2 loads)
// ---------------------------------------------------------------------------
__global__ void final_kernel(const float* __restrict__ sn,
                             const float* __restrict__ ptr_v,
                             const float* __restrict__ out2,
                             float* __restrict__ probs) {
    const int b = blockIdx.x >> 1;
    const int n0 = (blockIdx.x & 1) * 512;
    const int tid = threadIdx.x;
    __shared__ float pv_s[512], o2_s[512];
    pv_s[tid] = ptr_v[tid];
    pv_s[tid + 256] = ptr_v[tid + 256];
    o2_s[tid] = out2[b * Hd + tid];
    o2_s[tid + 256] = out2[b * Hd + tid + 256];
    __syncthreads();
    const float* base = sn + (size_t)b * Hd * Nn + n0 + tid * 2;
    float a0 = 0.f, a1 = 0.f;
#pragma unroll 8
    for (int h = 0; h < 512; ++h) {
        float2 d = *(const float2*)(base + (size_t)h * Nn);
        float o = o2_s[h], w = pv_s[h];
        a0 += w * tanh_fast(d.x + o);
        a1 += w * tanh_fast(d.y + o);
    }
    float* op = probs + b * Nn + n0 + tid * 2;
    op[0] = a0;
    op[1] = a1;
}

// ---------------------------------------------------------------------------
extern "C" void kernel_launch(void* const* d_in, const int* in_sizes, int n_in,
                              void* d_out, int out_size, void* d_ws, size_t ws_size,
                              hipStream_t stream) {
    const float* mc  = (const float*)d_in[0];
    const float* sn  = (const float*)d_in[1];
    const float* aW  = (const float*)d_in[2];
    const float* av  = (const float*)d_in[3];
    const float* pv  = (const float*)d_in[4];
    const float* f1W = (const float*)d_in[5];
    const float* f1b = (const float*)d_in[6];
    const float* f2W = (const float*)d_in[7];
    const float* f2b = (const float*)d_in[8];

    unsigned short* Wb = (unsigned short*)d_ws;          // 512*512 bf16 = 512 KB
    float* fws = (float*)(Wb + 512 * 512);
    float* mc_term = fws;                                // 65536 floats
    float* scores  = mc_term + Bn * Hd;                  // 131072 floats
    float* context = scores + Bn * Nn;                   // 65536
    float* out1    = context + Bn * Hd;                  // 65536
    float* out2    = out1 + Bn * Hd;                     // 65536
    float* probs   = (float*)d_out;

    convert_W_kernel<<<dim3(128), dim3(256), 0, stream>>>(aW, Wb);
    mc_term_kernel<<<dim3(16384), dim3(256), 0, stream>>>(mc, aW, mc_term);
    attn_score_kernel<<<dim3(2048), dim3(256), 0, stream>>>(sn, Wb, av, mc_term, scores);
    softmax_kernel<<<dim3(128), dim3(256), 0, stream>>>(scores);
    context_kernel<<<dim3(16384), dim3(256), 0, stream>>>(sn, scores, context);
    fc1_kernel<<<dim3(16384), dim3(256), 0, stream>>>(mc, context, f1W, f1b, out1);
    fc2_kernel<<<dim3(16384), dim3(256), 0, stream>>>(out1, f2W, f2b, out2);
    final_kernel<<<dim3(256), dim3(256), 0, stream>>>(sn, pv, out2, probs);
}